// Round 7
// baseline (970.194 us; speedup 1.0000x reference)
//
#include <hip/hip_runtime.h>
#include <stdint.h>

// Problem constants (fixed by the reference)
#define Bc 4
#define Sc 2048
#define Dc 768
#define Kc 8192
#define NSc 2
#define Mc (Bc*Sc)                      // 8192 tokens
#define EMB_ELEMS ((size_t)Mc*NSc*Dc)   // emb output floats; indices follow
#define MARGIN 0.125f

typedef __attribute__((ext_vector_type(8))) __bf16 bf16x8;
typedef __attribute__((ext_vector_type(4))) float f32x4;
typedef __attribute__((ext_vector_type(4))) unsigned short u16x4;

__device__ __forceinline__ unsigned short f2bf(float f){
  unsigned int u = __float_as_uint(f);
  u += 0x7FFFu + ((u >> 16) & 1u);       // round-to-nearest-even
  return (unsigned short)(u >> 16);
}
__device__ __forceinline__ float bf2f(unsigned short h){
  return __uint_as_float(((unsigned int)h) << 16);
}
// u8 UB dequant: q=255 saturates to +inf (always-suspect => sound)
__device__ __forceinline__ float dq_ub(int q){
  return (q == 255) ? 1e30f : (float)q * (1.0f/9.0f) - 2.0f;
}

// ---------------- K0: convert x,w f32 -> bf16 (into ws) ----------------
__global__ __launch_bounds__(256) void k_convert(const float4* __restrict__ x,
                                                 const float4* __restrict__ w,
                                                 u16x4* __restrict__ xb,
                                                 u16x4* __restrict__ wb){
  int i = blockIdx.x * 256 + threadIdx.x;
  float4 v = x[i];
  u16x4 o;
  o.x = f2bf(v.x); o.y = f2bf(v.y); o.z = f2bf(v.z); o.w = f2bf(v.w);
  xb[i] = o;
  v = w[i];
  o.x = f2bf(v.x); o.y = f2bf(v.y); o.z = f2bf(v.z); o.w = f2bf(v.w);
  wb[i] = o;
}

// ---------------- K1: bf16 MFMA GEMM + in-loop gumbel slice-max + UB stats ---
// stash: bf16 logits in [t][1][k>=4096] quadrant of out_ind (r6 scheme).
// stats: u8 UB per (t, s, 16-col slice) in first 512 B of out_emb row [t][s]
//        (select reads them, then overwrites with the emb gather).
// Gumbel streams through global_load_lds strips -> rides the SAME vmcnt(0)
// drain the A/B staging already pays (r4/r6 lesson: reg-loads/stores in the
// K-loop pay per-iter latency; global_load_lds does not).
#define BM 128
#define BN 128
#define BK 32

__global__ __launch_bounds__(256) void k_gemm(const unsigned short* __restrict__ xb,
                                              const unsigned short* __restrict__ wb,
                                              const float* __restrict__ gumbel,
                                              unsigned short* __restrict__ stash,
                                              uint8_t* stats){
  __shared__ unsigned short As[BM*BK];   // 8 KB linear (global_load_lds dest)
  __shared__ unsigned short Bs[BN*BK];   // 8 KB
  __shared__ float gstrip[2][2048];      // 2 x 8 KB gumbel strips (dbuf)
  __shared__ float gmaxf[2048];          // [row=t_local*2+s][8 slices] max_g

  const int tid  = threadIdx.x;
  const int lane = tid & 63;
  const int wid  = tid >> 6;             // 4 waves, 2x2 -> each owns 64x64 out
  const int wm   = wid >> 1;
  const int wn   = wid & 1;

  // XCD-aware swizzle (4096 blocks, 8 XCDs, 4096%8==0 -> bijective)
  const int bid  = (int)blockIdx.x;
  const int swz  = (bid & 7) * 512 + (bid >> 3);
  const int bm0  = (swz >> 6) * BM;      // token block
  const int bn0  = (swz & 63) * BN;      // code block

  f32x4 acc[4][4] = {};

  const int srow  = tid >> 2;
  const int scole = (tid & 3) * 8;
  const unsigned short* aS0 = xb + (size_t)(bm0 + srow) * Dc + scole;
  const unsigned short* aS1 = xb + (size_t)(bm0 + 64 + srow) * Dc + scole;
  const unsigned short* bS0 = wb + (size_t)(bn0 + srow) * Dc + scole;
  const unsigned short* bS1 = wb + (size_t)(bn0 + 64 + srow) * Dc + scole;
  unsigned short* aD0 = &As[wid * 512];
  unsigned short* aD1 = &As[2048 + wid * 512];
  unsigned short* bD0 = &Bs[wid * 512];
  unsigned short* bD1 = &Bs[2048 + wid * 512];

  const int fr  = lane & 15;
  const int fq  = lane >> 4;
  const int fk  = fq * 8;
  const int gl5 = lane >> 5, gl31 = lane & 31;   // gumbel staging ids

  for (int it = 0; it < Dc/BK; ++it) {   // 24 iterations
    __syncthreads();
    const int kt = it * BK;
    __builtin_amdgcn_global_load_lds((const __attribute__((address_space(1))) void*)(aS0 + kt),
                                     (__attribute__((address_space(3))) void*)aD0, 16, 0, 0);
    __builtin_amdgcn_global_load_lds((const __attribute__((address_space(1))) void*)(aS1 + kt),
                                     (__attribute__((address_space(3))) void*)aD1, 16, 0, 0);
    __builtin_amdgcn_global_load_lds((const __attribute__((address_space(1))) void*)(bS0 + kt),
                                     (__attribute__((address_space(3))) void*)bD0, 16, 0, 0);
    __builtin_amdgcn_global_load_lds((const __attribute__((address_space(1))) void*)(bS1 + kt),
                                     (__attribute__((address_space(3))) void*)bD1, 16, 0, 0);
    // gumbel strip loads: 2 calls x (4 waves x 1KB) = 16 rows of 512B per iter
    if (it < 16) {
      #pragma unroll
      for (int c = 0; c < 2; ++c) {
        const int R = it*16 + c*8 + wid*2 + gl5;           // row = t_local*2+s
        const float* gs = gumbel + ((size_t)(bm0 + (R >> 1)) * NSc + (R & 1)) * Kc
                                 + bn0 + gl31*4;
        __builtin_amdgcn_global_load_lds((const __attribute__((address_space(1))) void*)gs,
            (__attribute__((address_space(3))) void*)&gstrip[it & 1][c*1024 + wid*256], 16, 0, 0);
      }
    }
    __syncthreads();

    // consume prev strip: per-16-col-slice gumbel max -> gmaxf
    if (it >= 1 && it <= 16) {
      const int sl = tid >> 1, hf = tid & 1;               // 128 slices/strip
      const float* p = &gstrip[(it-1) & 1][(sl >> 3)*128 + (sl & 7)*16 + hf*8];
      const float4 a4 = *(const float4*)p;
      const float4 b4 = *(const float4*)(p + 4);
      float m = fmaxf(fmaxf(fmaxf(a4.x, a4.y), fmaxf(a4.z, a4.w)),
                      fmaxf(fmaxf(b4.x, b4.y), fmaxf(b4.z, b4.w)));
      m = fmaxf(m, __shfl_xor(m, 1));
      if (hf == 0) gmaxf[((it-1)*16 + (sl >> 3))*8 + (sl & 7)] = m;
    }

    bf16x8 a[4], b[4];
    #pragma unroll
    for (int i = 0; i < 4; i++) {
      a[i] = *(const bf16x8*)&As[(wm*64 + i*16 + fr) * BK + fk];
      b[i] = *(const bf16x8*)&Bs[(wn*64 + i*16 + fr) * BK + fk];
    }
    #pragma unroll
    for (int i = 0; i < 4; i++)
      #pragma unroll
      for (int j = 0; j < 4; j++)
        acc[i][j] = __builtin_amdgcn_mfma_f32_16x16x32_bf16(a[i], b[j], acc[i][j], 0, 0, 0);
  }
  __syncthreads();                        // gmaxf complete & visible

  // C-write to stash. C/D layout: col = lane&15, row = (lane>>4)*4 + reg
  const int crow0 = bm0 + wm*64 + fq*4;
  const int ccol0 = bn0 + wn*64 + fr;
  #pragma unroll
  for (int i = 0; i < 4; i++)
    #pragma unroll
    for (int j = 0; j < 4; j++)
      #pragma unroll
      for (int r = 0; r < 4; r++)
        stash[(size_t)(crow0 + i*16 + r) * 32768 + (ccol0 + j*16)] = f2bf(acc[i][j][r]);

  // stats epilogue: UB16 = max_l(slice from regs) + max_g + slack, u8 ceil
  #pragma unroll
  for (int i = 0; i < 4; i++) {
    #pragma unroll
    for (int j = 0; j < 4; j++) {
      #pragma unroll
      for (int r = 0; r < 4; r++) {
        float m = acc[i][j][r];
        m = fmaxf(m, __shfl_xor(m, 1)); m = fmaxf(m, __shfl_xor(m, 2));
        m = fmaxf(m, __shfl_xor(m, 4)); m = fmaxf(m, __shfl_xor(m, 8));
        if (fr == 0) {
          const int tl  = wm*64 + i*16 + fq*4 + r;         // token in block
          const int sb  = wn*4 + j;                         // slice in block
          const int slg = (bn0 >> 4) + sb;                  // global slice 0..511
          #pragma unroll
          for (int s = 0; s < 2; ++s) {
            const float ub = m + gmaxf[(tl*2 + s)*8 + sb] + 0.02f;
            int q = (int)ceilf((ub + 2.0f) * 9.0f);
            q = q < 0 ? 0 : (q > 255 ? 255 : q);
            stats[((size_t)(bm0 + tl)*NSc + s)*3072 + slg] = (uint8_t)q;
          }
        }
      }
    }
  }
}

// ---------------- K2: per-token wave select via UB pruning + outputs ---------
__global__ __launch_bounds__(256) void k_sel(const unsigned short* stash,   // aliases out_ind!
                                             const uint8_t* stats,          // aliases out_emb!
                                             const float* __restrict__ gumbel,
                                             const float* __restrict__ x,
                                             const float* __restrict__ w,
                                             const float* __restrict__ emb_tab,
                                             float* out_emb,
                                             float* out_ind){
  const int tid = threadIdx.x, lane = tid & 63, wid = tid >> 6;
  const int t = blockIdx.x * 4 + wid;     // one wave per token (both samples)
  __shared__ int ckk[4][16];              // per-wave candidate list

  const unsigned short* srow = stash + (size_t)t * 32768;
  int sel[2];

  #pragma unroll
  for (int s = 0; s < 2; ++s) {
    const float* grow = gumbel + ((size_t)t*NSc + s)*Kc;
    const uint8_t* st = stats + ((size_t)t*NSc + s)*3072;
    const uint2 qv = ((const uint2*)st)[lane];     // 8 slice UBs per lane
    float ub[8];
    #pragma unroll
    for (int p = 0; p < 4; ++p) ub[p]     = dq_ub((int)((qv.x >> (8*p)) & 255u));
    #pragma unroll
    for (int p = 0; p < 4; ++p) ub[4 + p] = dq_ub((int)((qv.y >> (8*p)) & 255u));

    // wave argmax-UB slice (tie -> min index)
    float bm = -1e30f; int bi = 0;
    #pragma unroll
    for (int p = 0; p < 8; ++p) if (ub[p] > bm) { bm = ub[p]; bi = lane*8 + p; }
    #pragma unroll
    for (int off = 1; off < 64; off <<= 1) {
      const float ov = __shfl_xor(bm, off); const int oi = __shfl_xor(bi, off);
      if (ov > bm || (ov == bm && oi < bi)) { bm = ov; bi = oi; }
    }
    // exact LB from best-UB slice
    float vb = -1e30f;
    if (lane < 16) { const int k = bi*16 + lane; vb = bf2f(srow[k]) + grow[k]; }
    #pragma unroll
    for (int off = 1; off < 64; off <<= 1) vb = fmaxf(vb, __shfl_xor(vb, off));
    const float thr = vb - 0.4f;

    // pass 1: walked max V over suspect slices
    float V = vb;
    #pragma unroll
    for (int p = 0; p < 8; ++p) {
      unsigned long long msk = __ballot(ub[p] >= thr);
      while (msk) {
        const int ln = (int)__ffsll(msk) - 1; msk &= msk - 1;
        const int sl = ln*8 + p;
        float vv = -1e30f;
        if (lane < 16) { const int k = sl*16 + lane; vv = bf2f(srow[k]) + grow[k]; }
        #pragma unroll
        for (int off = 1; off < 64; off <<= 1) vv = fmaxf(vv, __shfl_xor(vv, off));
        V = fmaxf(V, vv);
      }
    }
    // pass 2: candidates within MARGIN of V
    const float cthr = V - MARGIN;
    int cn = 0;
    #pragma unroll
    for (int p = 0; p < 8; ++p) {
      unsigned long long msk = __ballot(ub[p] >= thr);
      while (msk) {
        const int ln = (int)__ffsll(msk) - 1; msk &= msk - 1;
        const int sl = ln*8 + p;
        float vv = -1e30f;
        if (lane < 16) { const int k = sl*16 + lane; vv = bf2f(srow[k]) + grow[k]; }
        unsigned long long cm = __ballot(vv >= cthr);
        while (cm) {
          const int b = (int)__ffsll(cm) - 1; cm &= cm - 1;
          if (cn < 16) { ckk[wid][cn] = sl*16 + b; ++cn; }
        }
      }
    }
    // resolve
    if (cn == 1) {
      sel[s] = ckk[wid][0];
    } else {
      float best = -1e30f; int bk = 1 << 30;
      const float* xr = x + (size_t)t * Dc;
      for (int c = 0; c < cn; ++c) {
        const int kc = ckk[wid][c];
        const float* wr = w + (size_t)kc * Dc;
        double a = 0.0;
        #pragma unroll
        for (int d2 = 0; d2 < 12; ++d2) {
          const int d = lane + d2*64;
          a += (double)xr[d] * (double)wr[d];
        }
        #pragma unroll
        for (int off = 32; off; off >>= 1) a += __shfl_xor(a, off);
        const float ex = (float)a + grow[kc];
        if (ex > best || (ex == best && kc < bk)) { best = ex; bk = kc; }
      }
      sel[s] = bk;
    }
  }

  // writes: full one-hot rows (overwrites stash quadrant) + emb gathers
  #pragma unroll
  for (int s = 0; s < 2; ++s) {
    float* irow = out_ind + ((size_t)t*NSc + s)*Kc;
    const int target = sel[s];
    #pragma unroll
    for (int itw = 0; itw < 32; ++itw) {
      const int k0 = itw*256 + lane*4;
      float4 z = {0.f, 0.f, 0.f, 0.f};
      const int d = target - k0;
      if (d == 0) z.x = 1.0f; else if (d == 1) z.y = 1.0f;
      else if (d == 2) z.z = 1.0f; else if (d == 3) z.w = 1.0f;
      *(float4*)&irow[k0] = z;
    }
    const float* er = emb_tab + (size_t)target * Dc;
    float* eo = out_emb + ((size_t)t*NSc + s)*Dc;   // overwrites stats bytes
    #pragma unroll
    for (int i2 = 0; i2 < 3; ++i2) {
      const int d0 = i2*256 + lane*4;
      *(float4*)&eo[d0] = *(const float4*)&er[d0];
    }
  }
}

extern "C" void kernel_launch(void* const* d_in, const int* in_sizes, int n_in,
                              void* d_out, int out_size, void* d_ws, size_t ws_size,
                              hipStream_t stream) {
  const float* x   = (const float*)d_in[0];
  const float* w   = (const float*)d_in[1];
  const float* emb = (const float*)d_in[2];
  const float* gum = (const float*)d_in[3];

  float* out_emb = (float*)d_out;
  float* out_ind = out_emb + EMB_ELEMS;
  // bf16 logit stash: [t][1][k>=4096] quadrant == ushort index t*32768 + 24576
  unsigned short* stash = (unsigned short*)out_ind + 24576;
  uint8_t* stats = (uint8_t*)out_emb;     // first 512 B of each [t][s] emb row

  unsigned short* xb = (unsigned short*)d_ws;           // [M][D] bf16 (12.6 MB)
  unsigned short* wb = xb + (size_t)Mc * Dc;            // [K][D] bf16 (12.6 MB)

  const int n4 = (Mc * Dc) / 4;
  k_convert<<<n4 / 256, 256, 0, stream>>>((const float4*)x, (const float4*)w,
                                          (u16x4*)xb, (u16x4*)wb);
  k_gemm<<<4096, 256, 0, stream>>>(xb, wb, gum, stash, stats);
  k_sel<<<Mc / 4, 256, 0, stream>>>(stash, stats, gum, x, w, emb, out_emb, out_ind);
}

// Round 8
// 471.167 us; speedup vs baseline: 2.0591x; 2.0591x over previous
//
#include <hip/hip_runtime.h>
#include <stdint.h>

// Problem constants (fixed by the reference)
#define Bc 4
#define Sc 2048
#define Dc 768
#define Kc 8192
#define NSc 2
#define Mc (Bc*Sc)                      // 8192 tokens
#define EMB_ELEMS ((size_t)Mc*NSc*Dc)   // emb output floats; indices follow

typedef __attribute__((ext_vector_type(8))) __bf16 bf16x8;
typedef __attribute__((ext_vector_type(4))) float f32x4;
typedef __attribute__((ext_vector_type(4))) unsigned short u16x4;
typedef __attribute__((ext_vector_type(8))) unsigned short u16x8;

__device__ __forceinline__ unsigned short f2bf(float f){
  unsigned int u = __float_as_uint(f);
  u += 0x7FFFu + ((u >> 16) & 1u);       // round-to-nearest-even
  return (unsigned short)(u >> 16);
}
__device__ __forceinline__ float bf2f(unsigned short h){
  return __uint_as_float(((unsigned int)h) << 16);
}

// ---------------- K0: convert x,w f32 -> bf16 (into ws) ----------------
__global__ __launch_bounds__(256) void k_convert(const float4* __restrict__ x,
                                                 const float4* __restrict__ w,
                                                 u16x4* __restrict__ xb,
                                                 u16x4* __restrict__ wb){
  int i = blockIdx.x * 256 + threadIdx.x;
  float4 v = x[i];
  u16x4 o;
  o.x = f2bf(v.x); o.y = f2bf(v.y); o.z = f2bf(v.z); o.w = f2bf(v.w);
  xb[i] = o;
  v = w[i];
  o.x = f2bf(v.x); o.y = f2bf(v.y); o.z = f2bf(v.z); o.w = f2bf(v.w);
  wb[i] = o;
}

// ---------------- K1: bf16 MFMA GEMM (m97 loop untouched) --------------------
// Epilogue (all POST-loop — r4/r6/r7 lesson: nothing extra in the K-loop):
//  1) coalesced stash write via LDS transpose (4 chunks of 32 rows),
//  2) one-hot zero burst (fire-and-forget, no trailing barrier).
// Layout in out_ind (token row = 65536 B = [t][s][k] f32):
//   [t][0][*], [t][1][k<4096] : zeroed here.  [t][1][k>=4096]: bf16 stash.
#define BM 128
#define BN 128
#define BK 32

__global__ __launch_bounds__(256) void k_gemm(const unsigned short* __restrict__ xb,
                                              const unsigned short* __restrict__ wb,
                                              unsigned short* __restrict__ stash,
                                              float* __restrict__ out_ind){
  __shared__ __align__(16) unsigned short smem[8192];   // As|Bs, reused by transpose
  unsigned short* As = smem;
  unsigned short* Bs = smem + 4096;

  const int tid  = threadIdx.x;
  const int lane = tid & 63;
  const int wid  = tid >> 6;             // 4 waves, 2x2 -> each owns 64x64 out
  const int wm   = wid >> 1;
  const int wn   = wid & 1;

  // XCD-aware swizzle (4096 blocks, 8 XCDs, 4096%8==0 -> bijective)
  const int bid  = (int)blockIdx.x;
  const int swz  = (bid & 7) * 512 + (bid >> 3);
  const int bm0  = (swz >> 6) * BM;      // token block
  const int bn0  = (swz & 63) * BN;      // code block

  f32x4 acc[4][4] = {};

  const int srow  = tid >> 2;
  const int scole = (tid & 3) * 8;
  const unsigned short* aS0 = xb + (size_t)(bm0 + srow) * Dc + scole;
  const unsigned short* aS1 = xb + (size_t)(bm0 + 64 + srow) * Dc + scole;
  const unsigned short* bS0 = wb + (size_t)(bn0 + srow) * Dc + scole;
  const unsigned short* bS1 = wb + (size_t)(bn0 + 64 + srow) * Dc + scole;
  unsigned short* aD0 = &As[wid * 512];
  unsigned short* aD1 = &As[2048 + wid * 512];
  unsigned short* bD0 = &Bs[wid * 512];
  unsigned short* bD1 = &Bs[2048 + wid * 512];

  const int fr = lane & 15;
  const int fq = lane >> 4;
  const int fk = fq * 8;

  for (int it = 0; it < Dc/BK; ++it) {   // 24 iterations — m97 structure, untouched
    __syncthreads();
    const int kt = it * BK;
    __builtin_amdgcn_global_load_lds((const __attribute__((address_space(1))) void*)(aS0 + kt),
                                     (__attribute__((address_space(3))) void*)aD0, 16, 0, 0);
    __builtin_amdgcn_global_load_lds((const __attribute__((address_space(1))) void*)(aS1 + kt),
                                     (__attribute__((address_space(3))) void*)aD1, 16, 0, 0);
    __builtin_amdgcn_global_load_lds((const __attribute__((address_space(1))) void*)(bS0 + kt),
                                     (__attribute__((address_space(3))) void*)bD0, 16, 0, 0);
    __builtin_amdgcn_global_load_lds((const __attribute__((address_space(1))) void*)(bS1 + kt),
                                     (__attribute__((address_space(3))) void*)bD1, 16, 0, 0);
    __syncthreads();

    bf16x8 a[4], b[4];
    #pragma unroll
    for (int i = 0; i < 4; i++) {
      a[i] = *(const bf16x8*)&As[(wm*64 + i*16 + fr) * BK + fk];
      b[i] = *(const bf16x8*)&Bs[(wn*64 + i*16 + fr) * BK + fk];
    }
    #pragma unroll
    for (int i = 0; i < 4; i++)
      #pragma unroll
      for (int j = 0; j < 4; j++)
        acc[i][j] = __builtin_amdgcn_mfma_f32_16x16x32_bf16(a[i], b[j], acc[i][j], 0, 0, 0);
  }

  // ---- epilogue 1: coalesced stash write via LDS transpose -------------------
  // C/D layout: col = lane&15, row = (lane>>4)*4 + reg (validated r1..r6).
  // 4 chunks of 32 rows; LDS tile [32][136] ushort (272 B row stride: 16B-aligned).
  unsigned short (*tb)[136] = (unsigned short (*)[136])smem;
  #pragma unroll
  for (int h2 = 0; h2 < 4; ++h2) {
    __syncthreads();                     // buffer free (K-loop / prev chunk done)
    if (wm == (h2 >> 1)) {
      const int ib = (h2 & 1) * 2;
      #pragma unroll
      for (int di = 0; di < 2; ++di)
        #pragma unroll
        for (int j = 0; j < 4; ++j)
          #pragma unroll
          for (int r = 0; r < 4; ++r)
            tb[di*16 + fq*4 + r][wn*64 + j*16 + fr] = f2bf(acc[ib + di][j][r]);
    }
    __syncthreads();
    #pragma unroll
    for (int c = 0; c < 2; ++c) {
      const int n = c*256 + tid, row = n >> 4, f4c = n & 15;
      *(u16x8*)&stash[(size_t)(bm0 + h2*32 + row) * 32768 + bn0 + f4c*8] =
          *(const u16x8*)&tb[row][f4c*8];
    }
  }

  // ---- epilogue 2: one-hot zero burst (fire-and-forget; no barrier after) ----
  {
    const float4 z = {0.f, 0.f, 0.f, 0.f};
    const bool lo = (bn0 < 4096);
    #pragma unroll
    for (int p = 0; p < 16; ++p) {
      const int n = p*256 + tid, tok = n >> 5, c4 = n & 31;
      float4* zp = (float4*)out_ind + (size_t)(bm0 + tok)*4096 + (bn0 >> 2) + c4;
      zp[0] = z;                          // [t][0][bn0..bn0+128)
      if (lo) zp[2048] = z;               // [t][1][bn0..bn0+128), k<4096 half
    }
  }
}

// ---------------- K2: select (r6 lean, verbatim) -----------------------------
#define MARGIN 0.125f

__global__ __launch_bounds__(256) void k_select(const unsigned short* stash,    // aliases out_ind!
                                                const float* __restrict__ gumbel,
                                                const float* __restrict__ x,
                                                const float* __restrict__ w,
                                                const float* __restrict__ emb_tab,
                                                float* __restrict__ out_emb,
                                                float* out_ind){
  const int t   = blockIdx.x;
  const int tid = threadIdx.x;
  const int lane = tid & 63, wid = tid >> 6;

  __shared__ unsigned short Lrow[Kc];    // 16 KB bf16 logits row
  __shared__ float wmax[4];
  __shared__ int   cand_k[16];
  __shared__ float cand_g[16];
  __shared__ int   cand_cnt;
  __shared__ int   sel_idx[NSc];

  // stage logits row t into LDS (stash quadrant gets overwritten below)
  {
    const u16x4* src = (const u16x4*)(stash + (size_t)t * 32768);
    u16x4* dst = (u16x4*)Lrow;
    #pragma unroll
    for (int j = 0; j < 8; j++) dst[j*256 + tid] = src[j*256 + tid];
  }
  __syncthreads();

  for (int s = 0; s < NSc; ++s) {
    const float* grow = gumbel + ((size_t)t * NSc + s) * Kc;
    float4 vals[8];
    float m = -1e30f;
    #pragma unroll
    for (int j = 0; j < 8; j++) {
      float4 g4 = ((const float4*)grow)[j*256 + tid];
      u16x4 l4 = *(const u16x4*)&Lrow[j*1024 + tid*4];
      float4 v;
      v.x = bf2f(l4.x) + g4.x;
      v.y = bf2f(l4.y) + g4.y;
      v.z = bf2f(l4.z) + g4.z;
      v.w = bf2f(l4.w) + g4.w;
      vals[j] = v;
      m = fmaxf(m, fmaxf(fmaxf(v.x, v.y), fmaxf(v.z, v.w)));
    }
    #pragma unroll
    for (int off = 32; off; off >>= 1) m = fmaxf(m, __shfl_xor(m, off));
    if (lane == 0) wmax[wid] = m;
    __syncthreads();
    const float gmax = fmaxf(fmaxf(wmax[0], wmax[1]), fmaxf(wmax[2], wmax[3]));
    if (tid == 0) cand_cnt = 0;
    __syncthreads();

    const float thr = gmax - MARGIN;
    #pragma unroll
    for (int j = 0; j < 8; j++) {
      const int k0 = j*1024 + tid*4;
      float vv[4] = {vals[j].x, vals[j].y, vals[j].z, vals[j].w};
      #pragma unroll
      for (int q = 0; q < 4; q++) {
        if (vv[q] >= thr) {
          int p = atomicAdd(&cand_cnt, 1);
          if (p < 16) cand_k[p] = k0 + q;
        }
      }
    }
    __syncthreads();

    const int cnt = min(cand_cnt, 16);
    if (cnt == 1) {
      if (tid == 0) sel_idx[s] = cand_k[0];
    } else {
      // exact refine: wave `wid` takes candidates wid, wid+4, ...
      for (int c = wid; c < cnt; c += 4) {
        const int kc = cand_k[c];
        const float* wr = w + (size_t)kc * Dc;
        const float* xr = x + (size_t)t * Dc;
        double accd = 0.0;
        for (int d = lane; d < Dc; d += 64) accd += (double)xr[d] * (double)wr[d];
        #pragma unroll
        for (int off = 32; off; off >>= 1) accd += __shfl_xor(accd, off);
        if (lane == 0) cand_g[c] = (float)accd + grow[kc];
      }
      __syncthreads();
      if (tid == 0) {
        float bg = -1e30f; int bk = Kc;
        for (int c = 0; c < cnt; ++c) {
          const float gg = cand_g[c]; const int kk = cand_k[c];
          if (gg > bg || (gg == bg && kk < bk)) { bg = gg; bk = kk; }
        }
        sel_idx[s] = bk;
      }
    }
    __syncthreads();
  }

  // ---- lean writes: zero the stash quadrant [t][1][k>=4096], then the 1.0s.
  // Everything else was pre-zeroed by k_gemm.
  {
    float* row1hi = out_ind + (size_t)t*16384 + 8192 + 4096;
    float4 z = {0.f, 0.f, 0.f, 0.f};
    #pragma unroll
    for (int q = 0; q < 4; ++q)
      ((float4*)row1hi)[q*256 + tid] = z;
  }
  __syncthreads();                        // zero stores complete before the 1.0s
  if (tid == 0) {
    out_ind[(size_t)t*16384 +        sel_idx[0]] = 1.0f;
    out_ind[(size_t)t*16384 + 8192 + sel_idx[1]] = 1.0f;
  }

  // embedding gathers
  #pragma unroll
  for (int s = 0; s < NSc; ++s) {
    const int idx = sel_idx[s];
    const float* er = emb_tab + (size_t)idx * Dc;
    float* eo = out_emb + ((size_t)t*NSc + s)*Dc;
    for (int d = tid; d < Dc; d += 256) eo[d] = er[d];
  }
}

extern "C" void kernel_launch(void* const* d_in, const int* in_sizes, int n_in,
                              void* d_out, int out_size, void* d_ws, size_t ws_size,
                              hipStream_t stream) {
  const float* x   = (const float*)d_in[0];
  const float* w   = (const float*)d_in[1];
  const float* emb = (const float*)d_in[2];
  const float* gum = (const float*)d_in[3];

  float* out_emb = (float*)d_out;
  float* out_ind = out_emb + EMB_ELEMS;
  // bf16 logit stash: [t][1][k>=4096] quadrant == ushort index t*32768 + 24576
  unsigned short* stash = (unsigned short*)out_ind + 24576;

  unsigned short* xb = (unsigned short*)d_ws;           // [M][D] bf16 (12.6 MB)
  unsigned short* wb = xb + (size_t)Mc * Dc;            // [K][D] bf16 (12.6 MB)

  const int n4 = (Mc * Dc) / 4;
  k_convert<<<n4 / 256, 256, 0, stream>>>((const float4*)x, (const float4*)w,
                                          (u16x4*)xb, (u16x4*)wb);
  k_gemm<<<4096, 256, 0, stream>>>(xb, wb, stash, out_ind);
  k_select<<<Mc, 256, 0, stream>>>(stash, gum, x, w, emb, out_emb, out_ind);
}

// Round 9
// 381.854 us; speedup vs baseline: 2.5407x; 1.2339x over previous
//
#include <hip/hip_runtime.h>
#include <stdint.h>

// Problem constants (fixed by the reference)
#define Bc 4
#define Sc 2048
#define Dc 768
#define Kc 8192
#define NSc 2
#define Mc (Bc*Sc)                      // 8192 tokens
#define EMB_ELEMS ((size_t)Mc*NSc*Dc)   // emb output floats; indices follow

typedef __attribute__((ext_vector_type(8))) __bf16 bf16x8;
typedef __attribute__((ext_vector_type(4))) float f32x4;
typedef __attribute__((ext_vector_type(4))) unsigned short u16x4;

__device__ __forceinline__ unsigned short f2bf(float f){
  unsigned int u = __float_as_uint(f);
  u += 0x7FFFu + ((u >> 16) & 1u);       // round-to-nearest-even
  return (unsigned short)(u >> 16);
}
__device__ __forceinline__ float bf2f(unsigned short h){
  return __uint_as_float(((unsigned int)h) << 16);
}

// ---------------- K0: convert x,w f32 -> bf16 (into ws) ----------------
__global__ __launch_bounds__(256) void k_convert(const float4* __restrict__ x,
                                                 const float4* __restrict__ w,
                                                 u16x4* __restrict__ xb,
                                                 u16x4* __restrict__ wb){
  int i = blockIdx.x * 256 + threadIdx.x;
  float4 v = x[i];
  u16x4 o;
  o.x = f2bf(v.x); o.y = f2bf(v.y); o.z = f2bf(v.z); o.w = f2bf(v.w);
  xb[i] = o;
  v = w[i];
  o.x = f2bf(v.x); o.y = f2bf(v.y); o.z = f2bf(v.z); o.w = f2bf(v.w);
  wb[i] = o;
}

// ---------------- K1: 256x256 4-phase bf16 MFMA GEMM (T3+T4+T5+T2) ----------
// 8 waves (2M x 4N), BK=64, 128 KiB double-buffered LDS.
// Stage units (8 KB = 1 global_load_lds x 512 threads), issue order per tile:
//   slots {B0,B1,B2,B3,A0,A2,A1,A3}; 2 issued per phase, ONE TILE AHEAD.
// Counted vmcnt: ph0 waits oldest 6 (B0..B3,A0,A2) via vmcnt(2); ph1 waits
// A1,A3 via vmcnt(2) (leaves next tile's B01 in flight). Tail drains vmcnt(0).
// LDS XOR swizzle: data for k-block kb of row r lives at slot (kb ^ (r&7));
// write side achieved by pre-swizzling the GLOBAL source (linear LDS dest).
__global__ __launch_bounds__(512, 2) void k_gemm(const unsigned short* __restrict__ xb,
                                                 const unsigned short* __restrict__ wb,
                                                 unsigned short* __restrict__ stash){
  __shared__ __align__(16) unsigned char lds[131072];   // 2 x (A 32K | B 32K)

  const int tid  = threadIdx.x;
  const int lane = tid & 63;
  const int wid  = tid >> 6;             // 8 waves
  const int wr   = wid >> 2;             // M half (0..1)
  const int wc   = wid & 3;              // N quarter (0..3)
  const int fr   = lane & 15;
  const int fq   = lane >> 4;

  // XCD-aware swizzle (1024 blocks, 1024%8==0 -> bijective)
  const int bid = (int)blockIdx.x;
  const int swz = (bid & 7) * 128 + (bid >> 3);
  const int bm0 = (swz >> 5) * 256;      // token block
  const int bn0 = (swz & 31) * 256;      // code block

  f32x4 acc[8][4] = {};

  // ---- stage setup: slot s covers 64 rows x 64 cols (8 KB) of A or B
  const int rin   = tid >> 3;                 // row within unit (0..63)
  const int kblkp = (tid & 7) ^ (rin & 7);    // inverse-swizzled k-block
  const unsigned short* gsrc[8];
  unsigned dstoff[8];
  #pragma unroll
  for (int s = 0; s < 8; ++s) {
    const int isA = s >> 2;
    const int q   = s & 3;
    const int r64 = isA ? (((q & 1) << 1) | (q >> 1)) : q;   // A order 0,2,1,3
    const int grow = (isA ? bm0 : bn0) + r64 * 64 + rin;
    gsrc[s]   = (isA ? xb : wb) + (size_t)grow * Dc + kblkp * 8;
    dstoff[s] = (isA ? 0u : 32768u) + (unsigned)r64 * 8192u + (unsigned)wid * 1024u;
  }

#define ISSUE(s_, bo_) __builtin_amdgcn_global_load_lds( \
    (const __attribute__((address_space(1))) void*)gsrc[s_], \
    (__attribute__((address_space(3))) void*)&lds[(bo_) + dstoff[s_]], 16, 0, 0)

  // prologue: tile 0 -> buf0 (order matches steady-state ledger)
  #pragma unroll
  for (int s = 0; s < 8; ++s) ISSUE(s, 0u);
  #pragma unroll
  for (int s = 0; s < 8; ++s) gsrc[s] += 64;             // point at tile 1

  unsigned bufR = 0u, bufW = 65536u;
  const unsigned aRow = (unsigned)(wr*128 + fr) * 128u;            // A row byte
  const unsigned bRow = (unsigned)(wc*64  + fr) * 128u + 32768u;   // B row byte
  const unsigned sl0  = (unsigned)((fq       ) ^ (fr & 7)) * 16u;  // k-step 0 slot
  const unsigned sl1  = (unsigned)((fq + 4   ) ^ (fr & 7)) * 16u;  // k-step 1 slot

  for (int t = 0; t < 12; ++t) {
    const bool more = (t < 11);
    bf16x8 a[4], b0[4], b1[4];

    // ---------------- ph0: k-step 0, m-half 0 ----------------
    asm volatile("s_waitcnt vmcnt(2)" ::: "memory");     // B0..B3,A0,A2 of tile t done
    __builtin_amdgcn_s_barrier();
    asm volatile("" ::: "memory");
    if (more) { ISSUE(0, bufW); ISSUE(1, bufW); }
    #pragma unroll
    for (int n = 0; n < 4; ++n) b0[n] = *(const bf16x8*)&lds[bufR + bRow + (unsigned)n*2048u + sl0];
    #pragma unroll
    for (int m = 0; m < 4; ++m) a[m]  = *(const bf16x8*)&lds[bufR + aRow + (unsigned)m*2048u + sl0];
    __builtin_amdgcn_s_setprio(1);
    #pragma unroll
    for (int m = 0; m < 4; ++m)
      #pragma unroll
      for (int n = 0; n < 4; ++n)
        acc[m][n] = __builtin_amdgcn_mfma_f32_16x16x32_bf16(a[m], b0[n], acc[m][n], 0, 0, 0);
    __builtin_amdgcn_s_setprio(0);

    // ---------------- ph1: k-step 0, m-half 1 ----------------
    if (more) asm volatile("s_waitcnt vmcnt(2)" ::: "memory");   // A1,A3 of tile t done
    else      asm volatile("s_waitcnt vmcnt(0)" ::: "memory");
    __builtin_amdgcn_s_barrier();
    asm volatile("" ::: "memory");
    if (more) { ISSUE(2, bufW); ISSUE(3, bufW); }
    #pragma unroll
    for (int m = 0; m < 4; ++m) a[m] = *(const bf16x8*)&lds[bufR + aRow + 8192u + (unsigned)m*2048u + sl0];
    __builtin_amdgcn_s_setprio(1);
    #pragma unroll
    for (int m = 0; m < 4; ++m)
      #pragma unroll
      for (int n = 0; n < 4; ++n)
        acc[4+m][n] = __builtin_amdgcn_mfma_f32_16x16x32_bf16(a[m], b0[n], acc[4+m][n], 0, 0, 0);
    __builtin_amdgcn_s_setprio(0);

    // ---------------- ph2: k-step 1, m-half 0 (no wait/barrier needed) -------
    if (more) { ISSUE(4, bufW); ISSUE(5, bufW); }
    #pragma unroll
    for (int n = 0; n < 4; ++n) b1[n] = *(const bf16x8*)&lds[bufR + bRow + (unsigned)n*2048u + sl1];
    #pragma unroll
    for (int m = 0; m < 4; ++m) a[m]  = *(const bf16x8*)&lds[bufR + aRow + (unsigned)m*2048u + sl1];
    __builtin_amdgcn_s_setprio(1);
    #pragma unroll
    for (int m = 0; m < 4; ++m)
      #pragma unroll
      for (int n = 0; n < 4; ++n)
        acc[m][n] = __builtin_amdgcn_mfma_f32_16x16x32_bf16(a[m], b1[n], acc[m][n], 0, 0, 0);
    __builtin_amdgcn_s_setprio(0);

    // ---------------- ph3: k-step 1, m-half 1 ----------------
    if (more) { ISSUE(6, bufW); ISSUE(7, bufW); }
    #pragma unroll
    for (int m = 0; m < 4; ++m) a[m] = *(const bf16x8*)&lds[bufR + aRow + 8192u + (unsigned)m*2048u + sl1];
    __builtin_amdgcn_s_setprio(1);
    #pragma unroll
    for (int m = 0; m < 4; ++m)
      #pragma unroll
      for (int n = 0; n < 4; ++n)
        acc[4+m][n] = __builtin_amdgcn_mfma_f32_16x16x32_bf16(a[m], b1[n], acc[4+m][n], 0, 0, 0);
    __builtin_amdgcn_s_setprio(0);

    bufR ^= 65536u; bufW ^= 65536u;
    if (t < 10) {
      #pragma unroll
      for (int s = 0; s < 8; ++s) gsrc[s] += 64;
    }
  }
#undef ISSUE

  // C-write. C/D layout: col = lane&15, row = (lane>>4)*4 + reg (validated r1..r8)
  #pragma unroll
  for (int m = 0; m < 8; ++m)
    #pragma unroll
    for (int n = 0; n < 4; ++n)
      #pragma unroll
      for (int r = 0; r < 4; ++r)
        stash[(size_t)(bm0 + wr*128 + m*16 + fq*4 + r) * 32768
              + (bn0 + wc*64 + n*16 + fr)] = f2bf(acc[m][n][r]);
}

// ---------------- K2: select (r1 logic, verbatim) ----------------------------
#define MARGIN 0.125f

__global__ __launch_bounds__(256) void k_select(const unsigned short* logits,   // aliases out_ind!
                                                const float* __restrict__ gumbel,
                                                const float* __restrict__ x,
                                                const float* __restrict__ w,
                                                const float* __restrict__ emb_tab,
                                                float* __restrict__ out_emb,
                                                float* out_ind){
  const int t   = blockIdx.x;
  const int tid = threadIdx.x;
  const int lane = tid & 63, wid = tid >> 6;

  __shared__ unsigned short Lrow[Kc];    // 16 KB bf16 logits row
  __shared__ float wmax[4];
  __shared__ int   cand_k[16];
  __shared__ float cand_g[16];
  __shared__ int   cand_cnt;
  __shared__ int   sel_idx[NSc];

  // stage logits row t into LDS (before this block overwrites that memory)
  {
    const u16x4* src = (const u16x4*)(logits + (size_t)t * 32768);
    u16x4* dst = (u16x4*)Lrow;
    #pragma unroll
    for (int j = 0; j < 8; j++) dst[j*256 + tid] = src[j*256 + tid];
  }
  __syncthreads();

  for (int s = 0; s < NSc; ++s) {
    const float* grow = gumbel + ((size_t)t * NSc + s) * Kc;
    float4 vals[8];
    float m = -1e30f;
    #pragma unroll
    for (int j = 0; j < 8; j++) {
      float4 g4 = ((const float4*)grow)[j*256 + tid];
      u16x4 l4 = *(const u16x4*)&Lrow[j*1024 + tid*4];
      float4 v;
      v.x = bf2f(l4.x) + g4.x;
      v.y = bf2f(l4.y) + g4.y;
      v.z = bf2f(l4.z) + g4.z;
      v.w = bf2f(l4.w) + g4.w;
      vals[j] = v;
      m = fmaxf(m, fmaxf(fmaxf(v.x, v.y), fmaxf(v.z, v.w)));
    }
    #pragma unroll
    for (int off = 32; off; off >>= 1) m = fmaxf(m, __shfl_xor(m, off));
    if (lane == 0) wmax[wid] = m;
    __syncthreads();
    const float gmax = fmaxf(fmaxf(wmax[0], wmax[1]), fmaxf(wmax[2], wmax[3]));
    if (tid == 0) cand_cnt = 0;
    __syncthreads();

    const float thr = gmax - MARGIN;
    #pragma unroll
    for (int j = 0; j < 8; j++) {
      const int k0 = j*1024 + tid*4;
      float vv[4] = {vals[j].x, vals[j].y, vals[j].z, vals[j].w};
      #pragma unroll
      for (int q = 0; q < 4; q++) {
        if (vv[q] >= thr) {
          int p = atomicAdd(&cand_cnt, 1);
          if (p < 16) cand_k[p] = k0 + q;
        }
      }
    }
    __syncthreads();

    const int cnt = min(cand_cnt, 16);
    int idx;
    if (cnt == 1) {
      idx = cand_k[0];
    } else {
      // exact refine: wave `wid` takes candidates wid, wid+4, ...
      for (int c = wid; c < cnt; c += 4) {
        const int kc = cand_k[c];
        const float* wr = w + (size_t)kc * Dc;
        const float* xr = x + (size_t)t * Dc;
        double accd = 0.0;
        for (int d = lane; d < Dc; d += 64) accd += (double)xr[d] * (double)wr[d];
        #pragma unroll
        for (int off = 32; off; off >>= 1) accd += __shfl_xor(accd, off);
        if (lane == 0) cand_g[c] = (float)accd + grow[kc];  // f32 add, like ref
      }
      __syncthreads();
      if (tid == 0) {
        float bg = -1e30f; int bk_ = Kc;
        for (int c = 0; c < cnt; c++) {
          float g = cand_g[c]; int kk = cand_k[c];
          if (g > bg || (g == bg && kk < bk_)) { bg = g; bk_ = kk; }
        }
        sel_idx[s] = bk_;
      }
      __syncthreads();
      idx = sel_idx[s];
    }
    if (cnt == 1 && tid == 0) sel_idx[s] = idx;
    __syncthreads();

    // write one-hot indices row (overwrites the staged logits region for s=0)
    float* irow = out_ind + ((size_t)t * NSc + s) * Kc;
    #pragma unroll
    for (int j = 0; j < 8; j++) {
      const int k0 = j*1024 + tid*4;
      float4 z = {0.f, 0.f, 0.f, 0.f};
      const int d = sel_idx[s] - k0;
      if (d == 0) z.x = 1.0f; else if (d == 1) z.y = 1.0f;
      else if (d == 2) z.z = 1.0f; else if (d == 3) z.w = 1.0f;
      ((float4*)irow)[j*256 + tid] = z;
    }
    // gather embedding row
    const float* er = emb_tab + (size_t)sel_idx[s] * Dc;
    float* eo = out_emb + ((size_t)t * NSc + s) * Dc;
    for (int d = tid; d < Dc; d += 256) eo[d] = er[d];
    __syncthreads();   // protect shared reuse for next sample
  }
}

extern "C" void kernel_launch(void* const* d_in, const int* in_sizes, int n_in,
                              void* d_out, int out_size, void* d_ws, size_t ws_size,
                              hipStream_t stream) {
  const float* x   = (const float*)d_in[0];
  const float* w   = (const float*)d_in[1];
  const float* emb = (const float*)d_in[2];
  const float* gum = (const float*)d_in[3];

  float* out_emb = (float*)d_out;
  float* out_ind = out_emb + EMB_ELEMS;
  // bf16 logits staged inside the indices region: token row t at ushort t*32768
  unsigned short* stash = (unsigned short*)out_ind;

  unsigned short* xb = (unsigned short*)d_ws;           // [M][D] bf16 (12.6 MB)
  unsigned short* wb = xb + (size_t)Mc * Dc;            // [K][D] bf16 (12.6 MB)

  const int n4 = (Mc * Dc) / 4;
  k_convert<<<n4 / 256, 256, 0, stream>>>((const float4*)x, (const float4*)w,
                                          (u16x4*)xb, (u16x4*)wb);
  k_gemm<<<1024, 512, 0, stream>>>(xb, wb, stash);
  k_select<<<Mc, 256, 0, stream>>>(stash, gum, x, w, emb, out_emb, out_ind);
}